// Round 8
// baseline (6079.425 us; speedup 1.0000x reference)
//
#include <hip/hip_runtime.h>
#include <hip/hip_bf16.h>

#define GN 16384
#define GH 16
#define GK 16
#define GL 4
#define HPS 20            // padded h row: 16 features + sq + 3 pad (80 B)

#define RPB 32            // rows per knn block
#define CAP 160           // collect buffer capacity per row
#define BSTR 161          // buffer row stride
#define SSTR 264          // phase-A merge row stride (256 vals + pad)
#define INFF __builtin_inff()

// margin constants: analysis bound ~2^-15*(sqi+sqj); 32x safety
#define C1H  9.765625e-4f   // 2^-10
#define EPSM 4.8828125e-4f  // 2^-11

typedef __attribute__((ext_vector_type(8)))  short v8s;
typedef __attribute__((ext_vector_type(16))) float f32x16;

// workspace float-offsets
#define OFF_H     0
#define OFF_IDX   (5*GN*HPS)
#define OFF_FLAGS (OFF_IDX + GN*GK)
#define OFF_XF    (OFF_FLAGS + GN)
#define OFF_EMBW  (OFF_XF + GN*3)
#define OFF_EMBB  (OFF_EMBW + 3*GH)
#define OFF_W1    (OFF_EMBB + GH)
#define OFF_B1    (OFF_W1 + GL*2*GH*GH)
#define OFF_W2    (OFF_B1 + GL*GH)
#define OFF_B2    (OFF_W2 + GL*GH*GH)
#define OFF_OW    (OFF_B2 + GL*GH)
#define OFF_OB    (OFF_OW + GL*GH*3)
#define OFF_DFLAG (OFF_OB + 4)
#define OFF_HA    (OFF_DFLAG + 8)       // GN*16 bf16 = GN*8 floats
#define OFF_HB    (OFF_HA + GN*8)
#define OFF_TAB   (OFF_HB + GN*8)       // 64*16 ints layout table
#define OFF_PBAD  (OFF_TAB + 1024)

// ---------------------------------------------------------------------------
__global__ void detect_kernel(const unsigned short* __restrict__ raw,
                              int* __restrict__ flag)
{
    if (threadIdx.x == 0 && blockIdx.x == 0) {
        int cnt = 0;
        for (int i = 0; i < 64; ++i) {
            unsigned int bits = ((unsigned int)raw[2*i]) << 16;
            float v = __uint_as_float(bits);
            float a = fabsf(v);
            if (a > 1e-4f && a < 50.f) ++cnt;
        }
        *flag = (cnt >= 32) ? 1 : 0;
    }
}

__global__ void convert_kernel(const void* __restrict__ src,
                               float* __restrict__ dst, int n,
                               const int* __restrict__ flag)
{
    int i = blockIdx.x * 256 + threadIdx.x;
    if (i >= n) return;
    if (*flag)
        dst[i] = __bfloat162float(((const __hip_bfloat16*)src)[i]);
    else
        dst[i] = ((const float*)src)[i];
}

// ---------------------------------------------------------------------------
__device__ __forceinline__ float distt(const float hi[16], float sqi,
                                       const float* __restrict__ hj)
{
    float4 A = *(const float4*)(hj + 0);
    float4 B = *(const float4*)(hj + 4);
    float4 C = *(const float4*)(hj + 8);
    float4 D = *(const float4*)(hj + 12);
    float sqj = hj[16];
    float d0 = hi[0]*A.x;
    float d1 = hi[1]*A.y;
    d0 = fmaf(hi[2],  A.z, d0);  d1 = fmaf(hi[3],  A.w, d1);
    d0 = fmaf(hi[4],  B.x, d0);  d1 = fmaf(hi[5],  B.y, d1);
    d0 = fmaf(hi[6],  B.z, d0);  d1 = fmaf(hi[7],  B.w, d1);
    d0 = fmaf(hi[8],  C.x, d0);  d1 = fmaf(hi[9],  C.y, d1);
    d0 = fmaf(hi[10], C.z, d0);  d1 = fmaf(hi[11], C.w, d1);
    d0 = fmaf(hi[12], D.x, d0);  d1 = fmaf(hi[13], D.y, d1);
    d0 = fmaf(hi[14], D.z, d0);  d1 = fmaf(hi[15], D.w, d1);
    return fmaf(-2.f, d0 + d1, sqi + sqj);
}

#define LOAD_HI(ptr)                                                        \
    float hi[16]; float sqi;                                                \
    {                                                                       \
        const float* _hr = (ptr);                                           \
        float4 A = *(const float4*)(_hr + 0);                               \
        float4 B = *(const float4*)(_hr + 4);                               \
        float4 C = *(const float4*)(_hr + 8);                               \
        float4 D = *(const float4*)(_hr + 12);                              \
        hi[0]=A.x; hi[1]=A.y; hi[2]=A.z; hi[3]=A.w;                         \
        hi[4]=B.x; hi[5]=B.y; hi[6]=B.z; hi[7]=B.w;                         \
        hi[8]=C.x; hi[9]=C.y; hi[10]=C.z; hi[11]=C.w;                       \
        hi[12]=D.x; hi[13]=D.y; hi[14]=D.z; hi[15]=D.w;                     \
        sqi = _hr[16];                                                      \
    }

// ---------------------------------------------------------------------------
__global__ __launch_bounds__(256) void embed_kernel(
    const float* __restrict__ xf, const float* __restrict__ W,
    const float* __restrict__ b, float* __restrict__ h0)
{
    int i = blockIdx.x * 256 + threadIdx.x;
    float x0 = xf[i*3+0], x1 = xf[i*3+1], x2 = xf[i*3+2];
    float* orow = h0 + i * HPS;
    float sq = 0.f;
#pragma unroll
    for (int c = 0; c < GH; ++c) {
        float t = b[c];
        t = fmaf(x0, W[0*GH+c], t);
        t = fmaf(x1, W[1*GH+c], t);
        t = fmaf(x2, W[2*GH+c], t);
        t = fmaxf(t, 0.f);
        orow[c] = t;
        sq = fmaf(t, t, sq);
    }
    orow[16] = sq;
}

// ---------------------------------------------------------------------------
__global__ __launch_bounds__(256) void bfsplit_kernel(
    const float* __restrict__ hp, unsigned short* __restrict__ ha,
    unsigned short* __restrict__ hb)
{
    int i = blockIdx.x * 256 + threadIdx.x;     // over GN*16
    int row = i >> 4, f = i & 15;
    float x = hp[row*HPS + f];
    __hip_bfloat16 a = __float2bfloat16(x);
    float af = __bfloat162float(a);
    __hip_bfloat16 b = __float2bfloat16(x - af);
    ha[i] = *(unsigned short*)&a;
    hb[i] = *(unsigned short*)&b;
}

// ---------------------------------------------------------------------------
// Discover the MFMA 32x32x16 lane attribution empirically:
//   c1 = mfma(enc,ones): c1[reg] = 16*(rho+1), rho = lrow of lane feeding the ROW
//   c2 = mfma(ones,enc): c2[reg] = 16*(lam+1), lam = lrow of lane feeding the COL
// (k-arrangement cancels in the k-sum). Validated; failure -> pbad -> rescue.
__global__ void probe_kernel(int* __restrict__ table, int* __restrict__ pbad)
{
    const int lane = threadIdx.x;               // 64 threads, 1 block
    const int lrow = lane & 31;
    __hip_bfloat16 ev = __float2bfloat16((float)(lrow + 1));
    __hip_bfloat16 ov = __float2bfloat16(1.0f);
    short eb = *(short*)&ev, ob = *(short*)&ov;
    v8s enc, one;
#pragma unroll
    for (int e = 0; e < 8; ++e) { enc[e] = eb; one[e] = ob; }
    f32x16 z = {0.f,0.f,0.f,0.f,0.f,0.f,0.f,0.f,0.f,0.f,0.f,0.f,0.f,0.f,0.f,0.f};
    f32x16 c1 = __builtin_amdgcn_mfma_f32_32x32x16_bf16(enc, one, z, 0, 0, 0);
    f32x16 c2 = __builtin_amdgcn_mfma_f32_32x32x16_bf16(one, enc, z, 0, 0, 0);
    int badl = 0;
#pragma unroll
    for (int reg = 0; reg < 16; ++reg) {
        float fr = c1[reg] * 0.0625f - 1.f;
        float fl = c2[reg] * 0.0625f - 1.f;
        int ri = (int)floorf(fr + 0.5f);
        int li = (int)floorf(fl + 0.5f);
        if (fabsf(fr - (float)ri) > 1e-3f || ri < 0 || ri > 31 ||
            fabsf(fl - (float)li) > 1e-3f || li < 0 || li > 31) badl = 1;
        table[lane*16 + reg] = (ri & 255) | ((li & 255) << 8);
    }
    unsigned long long bm = __ballot(badl != 0);
    if (lane == 0) *pbad = (bm != 0ull) ? 1 : 0;
}

// ---------------------------------------------------------------------------
// MFMA kNN with probed layout tables; margin-collect superset; exact recheck.
__global__ __launch_bounds__(256, 1) void knn8_kernel(
    const float* __restrict__ hp,
    const unsigned short* __restrict__ ha, const unsigned short* __restrict__ hb,
    const int* __restrict__ table, const int* __restrict__ pbad,
    int* __restrict__ idxout, int* __restrict__ flags)
{
    __shared__ float    smp[RPB*SSTR];
    __shared__ int      bufj[RPB*BSTR];
    __shared__ unsigned cnt[RPB];
    __shared__ float    t16s[RPB];
    __shared__ int      badsh;

    const int tid   = threadIdx.x;
    const int w     = tid >> 6;             // wave 0..3
    const int lane  = tid & 63;
    const int lrow  = lane & 31;
    const int lhalf = lane >> 5;
    const int r0    = blockIdx.x * RPB;
    const int gbad  = *pbad;

    if (tid == 0) badsh = 0;
    if (tid < RPB) cnt[tid] = 0;
    __syncthreads();

    // layout tables for this lane
    int pk[16];
    {
        const int4* tp = (const int4*)(table + lane*16);
        int4 a = tp[0], b = tp[1], c = tp[2], d = tp[3];
        pk[0]=a.x; pk[1]=a.y; pk[2]=a.z; pk[3]=a.w;
        pk[4]=b.x; pk[5]=b.y; pk[6]=b.z; pk[7]=b.w;
        pk[8]=c.x; pk[9]=c.y; pk[10]=c.z; pk[11]=c.w;
        pk[12]=d.x; pk[13]=d.y; pk[14]=d.z; pk[15]=d.w;
    }

    // A fragments: lane loads point (r0+lrow), elements f = 8*lhalf..+8
    v8s Aa = *(const v8s*)(ha + (r0 + lrow)*16 + 8*lhalf);
    v8s Ab = *(const v8s*)(hb + (r0 + lrow)*16 + 8*lhalf);

    float srow[16];
#pragma unroll
    for (int reg = 0; reg < 16; ++reg)
        srow[reg] = hp[(r0 + (pk[reg] & 255))*HPS + 16];

    // ---- phase A: sample every 4th column; branchless per-(thread,reg) top-2
    // of v = d~ + C1H*sqj. Self-sample excluded via precomputed tsel.
    int tsel[16];
#pragma unroll
    for (int reg = 0; reg < 16; ++reg) {
        int rho = pk[reg] & 255, lam = (pk[reg] >> 8) & 255;
        int num = r0 + rho - 128*w - 4*lam;
        tsel[reg] = (num >= 0 && (num & 511) == 0) ? (num >> 9) : -1;
    }
    float m1[16], m2[16];
#pragma unroll
    for (int e = 0; e < 16; ++e) { m1[e] = INFF; m2[e] = INFF; }

    for (int t = 0; t < 32; ++t) {
        const int jb = 4*((w + 4*t)*32 + lrow);
        v8s Ba = *(const v8s*)(ha + jb*16 + 8*lhalf);
        v8s Bb = *(const v8s*)(hb + jb*16 + 8*lhalf);
        const float sqc = hp[jb*HPS + 16];
        f32x16 c = {0.f,0.f,0.f,0.f,0.f,0.f,0.f,0.f,0.f,0.f,0.f,0.f,0.f,0.f,0.f,0.f};
        c = __builtin_amdgcn_mfma_f32_32x32x16_bf16(Aa, Ba, c, 0, 0, 0);
        c = __builtin_amdgcn_mfma_f32_32x32x16_bf16(Aa, Bb, c, 0, 0, 0);
        c = __builtin_amdgcn_mfma_f32_32x32x16_bf16(Ab, Ba, c, 0, 0, 0);
        if (t == 0) {
            // numeric self-test on reg 0 (skip if it's the self pair)
            int rho = pk[0] & 255, lam = (pk[0] >> 8) & 255;
            int jc = 4*(w*32 + lam);
            if (jc != r0 + rho) {
                float dmf = fmaf(-2.f, c[0], srow[0] + sqc);
                float hiv[16];
#pragma unroll
                for (int f = 0; f < 16; ++f) hiv[f] = hp[(r0 + rho)*HPS + f];
                float dex = distt(hiv, srow[0], hp + jc*HPS);
                float tol = C1H*(srow[0] + sqc) + EPSM;
                if (!(fabsf(dmf - dex) <= tol)) badsh = 1;
            }
        }
        const float bba = fmaf(C1H, sqc, sqc);   // sqc*(1+C1H)
#pragma unroll
        for (int reg = 0; reg < 16; ++reg) {
            float v = fmaf(-2.f, c[reg], srow[reg]) + bba;
            if (t == tsel[reg]) v = INFF;
            float h2 = fmaxf(m1[reg], v);
            m1[reg] = fminf(m1[reg], v);
            m2[reg] = fminf(m2[reg], h2);
        }
    }
    __syncthreads();
#pragma unroll
    for (int reg = 0; reg < 16; ++reg) {
        int rho = pk[reg] & 255, lam = (pk[reg] >> 8) & 255;
        smp[rho*SSTR + w*64 + lam*2 + 0] = m1[reg];
        smp[rho*SSTR + w*64 + lam*2 + 1] = m2[reg];
    }
    __syncthreads();

    // ---- merge: 16th smallest of 256 sample-values per row (8 lanes/row)
    const int mr = tid >> 3, g = tid & 7;
    {
        float sv[32];
#pragma unroll
        for (int e = 0; e < 8; ++e) {
            float4 u = *(const float4*)(smp + mr*SSTR + g*32 + e*4);
            sv[e*4+0] = u.x; sv[e*4+1] = u.y; sv[e*4+2] = u.z; sv[e*4+3] = u.w;
        }
        float tv = INFF;
#pragma unroll
        for (int k = 0; k < 16; ++k) {
            float md = sv[0]; int ms = 0;
#pragma unroll
            for (int e = 1; e < 32; ++e) { bool cs = (sv[e] < md); md = cs ? sv[e] : md; ms = cs ? e : ms; }
            float rv = md; int rl = g;
#pragma unroll
            for (int mm = 1; mm <= 4; mm <<= 1) {
                float ov = __shfl_xor(rv, mm, 8);
                int   ol = __shfl_xor(rl, mm, 8);
                bool cs = (ov < rv) || (ov == rv && ol < rl);
                rv = cs ? ov : rv; rl = cs ? ol : rl;
            }
            tv = rv;
            if (rl == g) {
#pragma unroll
                for (int e = 0; e < 32; ++e) if (e == ms) sv[e] = INFF;
            }
        }
        if (g == 0) t16s[mr] = tv;
    }
    __syncthreads();

    float TR[16];
#pragma unroll
    for (int reg = 0; reg < 16; ++reg)
        TR[reg] = t16s[pk[reg] & 255] + fmaf(2.f*C1H, srow[reg], 2.f*EPSM);

    // ---- phase B: full scan; collect d~ - C1H*sqj <= TR (self collected,
    // excluded in the exact recheck).
    for (int t = 0; t < 128; ++t) {
        const int jb = (w + 4*t)*32 + lrow;
        v8s Ba = *(const v8s*)(ha + jb*16 + 8*lhalf);
        v8s Bb = *(const v8s*)(hb + jb*16 + 8*lhalf);
        const float sqc = hp[jb*HPS + 16];
        f32x16 c = {0.f,0.f,0.f,0.f,0.f,0.f,0.f,0.f,0.f,0.f,0.f,0.f,0.f,0.f,0.f,0.f};
        c = __builtin_amdgcn_mfma_f32_32x32x16_bf16(Aa, Ba, c, 0, 0, 0);
        c = __builtin_amdgcn_mfma_f32_32x32x16_bf16(Aa, Bb, c, 0, 0, 0);
        c = __builtin_amdgcn_mfma_f32_32x32x16_bf16(Ab, Ba, c, 0, 0, 0);
        const float bbb = fmaf(-C1H, sqc, sqc);  // sqc*(1-C1H)
        const int jb0 = 32*(w + 4*t);
#pragma unroll
        for (int reg = 0; reg < 16; ++reg) {
            float dpr = fmaf(-2.f, c[reg], srow[reg]) + bbb;
            if (dpr <= TR[reg]) {
                int rho = pk[reg] & 255, lam = (pk[reg] >> 8) & 255;
                unsigned pos = atomicAdd(&cnt[rho], 1u);
                if (pos < CAP) bufj[rho*BSTR + pos] = jb0 + lam;
            }
        }
    }
    __syncthreads();

    // ---- exact f32 recheck + top-16 select ((d,j) order, ref-identical)
    {
        const unsigned cc  = cnt[mr];
        const unsigned lim = cc < CAP ? cc : CAP;
        LOAD_HI(hp + (r0 + mr)*HPS);
        float sd[20]; int sj[20];
#pragma unroll
        for (int e = 0; e < 20; ++e) {
            unsigned p = (unsigned)g + 8u*e;
            bool v = p < lim;
            int j = v ? bufj[mr*BSTR + p] : 0x7fffffff;
            if (v && j != r0 + mr) {
                sj[e] = j;
                sd[e] = distt(hi, sqi, hp + j*HPS);
            } else { sd[e] = INFF; sj[e] = 0x7fffffff; }
        }
#pragma unroll
        for (int k = 0; k < GK; ++k) {
            float md = sd[0]; int mj = sj[0]; int ms = 0;
#pragma unroll
            for (int e = 1; e < 20; ++e) {
                bool cs = (sd[e] < md) || (sd[e] == md && sj[e] < mj);
                md = cs ? sd[e] : md; mj = cs ? sj[e] : mj; ms = cs ? e : ms;
            }
            float rd = md; int rj = mj;
#pragma unroll
            for (int mm = 1; mm <= 4; mm <<= 1) {
                float od = __shfl_xor(rd, mm, 8);
                int   oj = __shfl_xor(rj, mm, 8);
                bool cs = (od < rd) || (od == rd && oj < rj);
                rd = cs ? od : rd; rj = cs ? oj : rj;
            }
            if (g == 0) idxout[(r0 + mr)*GK + k] = rj;
            if (rd == md && rj == mj) {
#pragma unroll
                for (int e = 0; e < 20; ++e) if (e == ms) { sd[e] = INFF; sj[e] = 0x7fffffff; }
            }
        }
        if (g == 0)
            flags[r0 + mr] = (cc > CAP || cc < 16u || badsh || gbad) ? 1 : 0;
    }
}

// ---------------------------------------------------------------------------
// Exact full-scan fallback for flagged rows.
__global__ __launch_bounds__(64) void rescue_kernel(
    const float* __restrict__ hp, const int* __restrict__ flags,
    int* __restrict__ idxout)
{
    const int lane = threadIdx.x;
    const int r0 = blockIdx.x * RPB;
    int f = (lane < RPB) ? flags[r0 + lane] : 0;
    if (__ballot(f != 0) == 0ull) return;
    for (int rr = 0; rr < RPB; ++rr) {
        if (flags[r0 + rr] == 0) continue;
        const int row = r0 + rr;
        LOAD_HI(hp + row * HPS);
        float topd[GK]; int topi[GK];
#pragma unroll
        for (int s = 0; s < GK; ++s) { topd[s] = INFF; topi[s] = -1; }
        float mx = INFF; int mxs = 0;
        for (int s = 0; s < GN/64; ++s) {
            int j = lane + (s << 6);
            float d = distt(hi, sqi, hp + j * HPS);
            if (j == row) d = INFF;
            if (d < mx) {
#pragma unroll
                for (int e = 0; e < GK; ++e) { bool cs = (e == mxs); topd[e] = cs ? d : topd[e]; topi[e] = cs ? j : topi[e]; }
                mx = topd[0]; mxs = 0;
#pragma unroll
                for (int e = 1; e < GK; ++e) { bool cs = (topd[e] >= mx); mx = cs ? topd[e] : mx; mxs = cs ? e : mxs; }
            }
        }
#pragma unroll
        for (int t = 0; t < GK; ++t) {
            float md = topd[0]; int mj = topi[0]; int ms = 0;
#pragma unroll
            for (int e = 1; e < GK; ++e) {
                bool cs = (topd[e] < md) || (topd[e] == md && topi[e] < mj);
                md = cs ? topd[e] : md; mj = cs ? topi[e] : mj; ms = cs ? e : ms;
            }
            float rd = md; int rj = mj;
#pragma unroll
            for (int m = 1; m <= 32; m <<= 1) {
                float od = __shfl_xor(rd, m, 64);
                int   oj = __shfl_xor(rj, m, 64);
                bool cs = (od < rd) || (od == rd && oj < rj);
                rd = cs ? od : rd; rj = cs ? oj : rj;
            }
            if (lane == 0) idxout[row*GK + t] = rj;
            if (rd == md && rj == mj) {
#pragma unroll
                for (int e = 0; e < GK; ++e) if (e == ms) { topd[e] = INFF; topi[e] = 0x7fffffff; }
            }
        }
    }
}

// ---------------------------------------------------------------------------
__global__ __launch_bounds__(256) void edgeconv_kernel(
    const float* __restrict__ hin, const int* __restrict__ idx,
    const float* __restrict__ W1, const float* __restrict__ b1,
    const float* __restrict__ W2, const float* __restrict__ b2,
    float* __restrict__ hout)
{
    __shared__ float sW1[2*GH*GH], sW2[GH*GH], sb1[GH], sb2[GH];
    const int tid = threadIdx.x;
    for (int t = tid; t < 2*GH*GH; t += 256) sW1[t] = W1[t];
    for (int t = tid; t < GH*GH;  t += 256) sW2[t] = W2[t];
    if (tid < GH) { sb1[tid] = b1[tid]; sb2[tid] = b2[tid]; }
    __syncthreads();

    const int t4 = tid & 3;
    const int i = blockIdx.x * 64 + (tid >> 2);

    LOAD_HI(hin + i * HPS);
    (void)sqi;
    float ci[GH];
#pragma unroll
    for (int c = 0; c < GH; ++c) {
        float s = sb1[c];
#pragma unroll
        for (int d = 0; d < GH; ++d) s = fmaf(hi[d], sW1[d*GH+c], s);
        ci[c] = s;
    }
    float acc[GH];
#pragma unroll
    for (int c = 0; c < GH; ++c) acc[c] = 0.f;

    const int4 jj = *(const int4*)(idx + i*GK + t4*4);
    const int js[4] = { jj.x, jj.y, jj.z, jj.w };
#pragma unroll
    for (int nn = 0; nn < 4; ++nn) {
        const int j = js[nn];
        float dj[GH];
        {
            const float* hv = hin + j * HPS;
            float4 A = *(const float4*)(hv + 0);
            float4 B = *(const float4*)(hv + 4);
            float4 C = *(const float4*)(hv + 8);
            float4 D = *(const float4*)(hv + 12);
            dj[0]=A.x-hi[0]; dj[1]=A.y-hi[1]; dj[2]=A.z-hi[2]; dj[3]=A.w-hi[3];
            dj[4]=B.x-hi[4]; dj[5]=B.y-hi[5]; dj[6]=B.z-hi[6]; dj[7]=B.w-hi[7];
            dj[8]=C.x-hi[8]; dj[9]=C.y-hi[9]; dj[10]=C.z-hi[10]; dj[11]=C.w-hi[11];
            dj[12]=D.x-hi[12]; dj[13]=D.y-hi[13]; dj[14]=D.z-hi[14]; dj[15]=D.w-hi[15];
        }
        float msg[GH];
#pragma unroll
        for (int c = 0; c < GH; ++c) {
            float s = ci[c];
#pragma unroll
            for (int d = 0; d < GH; ++d) s = fmaf(dj[d], sW1[(GH+d)*GH+c], s);
            msg[c] = fmaxf(s, 0.f);
        }
#pragma unroll
        for (int c2 = 0; c2 < GH; ++c2) {
            float s = acc[c2];
#pragma unroll
            for (int c = 0; c < GH; ++c) s = fmaf(msg[c], sW2[c*GH+c2], s);
            acc[c2] = s;
        }
    }
#pragma unroll
    for (int c = 0; c < GH; ++c) {
        acc[c] += __shfl_xor(acc[c], 1);
        acc[c] += __shfl_xor(acc[c], 2);
    }
    if (t4 == 0) {
        float* orow = hout + i * HPS;
        float sq = 0.f;
#pragma unroll
        for (int c = 0; c < GH; ++c) {
            float v = acc[c] * (1.f/16.f) + sb2[c];
            orow[c] = v;
            sq = fmaf(v, v, sq);
        }
        orow[16] = sq;
    }
}

// ---------------------------------------------------------------------------
__global__ __launch_bounds__(256) void out_kernel(
    const float* __restrict__ hbase, const float* __restrict__ W,
    const float* __restrict__ b, void* __restrict__ out,
    const int* __restrict__ flag)
{
    int i = blockIdx.x * 256 + threadIdx.x;
    float a0 = b[0], a1 = b[1], a2 = b[2];
#pragma unroll
    for (int l = 0; l < GL; ++l) {
        const float* hp = hbase + l * GN * HPS + i * HPS;
#pragma unroll
        for (int c = 0; c < GH; ++c) {
            const float v = hp[c];
            const float* wr = W + (l * GH + c) * 3;
            a0 = fmaf(v, wr[0], a0);
            a1 = fmaf(v, wr[1], a1);
            a2 = fmaf(v, wr[2], a2);
        }
    }
    if (*flag) {
        __hip_bfloat16* o = (__hip_bfloat16*)out;
        o[i*3+0] = __float2bfloat16(a0);
        o[i*3+1] = __float2bfloat16(a1);
        o[i*3+2] = __float2bfloat16(a2);
    } else {
        float* o = (float*)out;
        o[i*3+0] = a0; o[i*3+1] = a1; o[i*3+2] = a2;
    }
}

// ---------------------------------------------------------------------------
extern "C" void kernel_launch(void* const* d_in, const int* in_sizes, int n_in,
                              void* d_out, int out_size, void* d_ws, size_t ws_size,
                              hipStream_t stream)
{
    float* wsf  = (float*)d_ws;
    int* idxb   = (int*)(wsf + OFF_IDX);
    int* flagsb = (int*)(wsf + OFF_FLAGS);
    int* dflag  = (int*)(wsf + OFF_DFLAG);
    unsigned short* ha = (unsigned short*)(wsf + OFF_HA);
    unsigned short* hb = (unsigned short*)(wsf + OFF_HB);
    int* tab    = (int*)(wsf + OFF_TAB);
    int* pbad   = (int*)(wsf + OFF_PBAD);

    detect_kernel<<<1, 64, 0, stream>>>((const unsigned short*)d_in[0], dflag);
    probe_kernel<<<1, 64, 0, stream>>>(tab, pbad);

    const int segoff[9] = {OFF_XF, OFF_EMBW, OFF_EMBB, OFF_W1, OFF_B1,
                           OFF_W2, OFF_B2, OFF_OW, OFF_OB};
    const int segn[9]   = {GN*3, 3*GH, GH, GL*2*GH*GH, GL*GH,
                           GL*GH*GH, GL*GH, GL*GH*3, 3};
    for (int s = 0; s < 9; ++s)
        convert_kernel<<<(segn[s] + 255)/256, 256, 0, stream>>>(
            d_in[s], wsf + segoff[s], segn[s], dflag);

    embed_kernel<<<GN/256, 256, 0, stream>>>(
        wsf + OFF_XF, wsf + OFF_EMBW, wsf + OFF_EMBB, wsf + OFF_H);

    for (int l = 0; l < GL; ++l) {
        const float* hin = wsf + OFF_H + l*GN*HPS;
        float* hout      = wsf + OFF_H + (l+1)*GN*HPS;
        bfsplit_kernel<<<GN*GH/256, 256, 0, stream>>>(hin, ha, hb);
        knn8_kernel<<<GN/RPB, 256, 0, stream>>>(hin, ha, hb, tab, pbad,
                                                idxb, flagsb);
        rescue_kernel<<<GN/RPB, 64, 0, stream>>>(hin, flagsb, idxb);
        edgeconv_kernel<<<GN/64, 256, 0, stream>>>(hin, idxb,
            wsf + OFF_W1 + l*2*GH*GH, wsf + OFF_B1 + l*GH,
            wsf + OFF_W2 + l*GH*GH,  wsf + OFF_B2 + l*GH, hout);
    }

    out_kernel<<<GN/256, 256, 0, stream>>>(
        wsf + OFF_H + GN*HPS, wsf + OFF_OW, wsf + OFF_OB, d_out, dflag);
}

// Round 9
// 3669.579 us; speedup vs baseline: 1.6567x; 1.6567x over previous
//
#include <hip/hip_runtime.h>
#include <hip/hip_bf16.h>

#define GN 16384
#define GH 16
#define GK 16
#define GL 4
#define HPS 20            // padded h row: 16 features + sq + 3 pad (80 B)

#define RPB 32            // rows per knn block
#define CAP 160           // collect buffer capacity per row
#define BSTR 161          // buffer row stride
#define SSTR 264          // phase-A merge row stride (256 vals + pad)
#define INFF __builtin_inff()

#define EREL 1.220703125e-4f  // 2^-13  (true bound ~2^-16, 8x headroom)
#define EABS 4.8828125e-4f    // 2^-11

typedef __attribute__((ext_vector_type(8)))  short v8s;
typedef __attribute__((ext_vector_type(16))) float f32x16;

// workspace float-offsets
#define OFF_H     0
#define OFF_IDX   (5*GN*HPS)
#define OFF_FLAGS (OFF_IDX + GN*GK)
#define OFF_XF    (OFF_FLAGS + GN)
#define OFF_EMBW  (OFF_XF + GN*3)
#define OFF_EMBB  (OFF_EMBW + 3*GH)
#define OFF_W1    (OFF_EMBB + GH)
#define OFF_B1    (OFF_W1 + GL*2*GH*GH)
#define OFF_W2    (OFF_B1 + GL*GH)
#define OFF_B2    (OFF_W2 + GL*GH*GH)
#define OFF_OW    (OFF_B2 + GL*GH)
#define OFF_OB    (OFF_OW + GL*GH*3)
#define OFF_DFLAG (OFF_OB + 4)
#define OFF_HA    (OFF_DFLAG + 8)       // GN*16 bf16
#define OFF_HB    (OFF_HA + GN*8)
#define OFF_HS    (OFF_HB + GN*8)       // GN*2 bf16 sq-split = GN floats
#define OFF_TAB   (OFF_HS + GN)
#define OFF_PBAD  (OFF_TAB + 1024)
#define OFF_SP    (OFF_PBAD + 4)
#define OFF_INV   (OFF_SP + 16)
#define OFF_SQM   (OFF_INV + 16)

// ---------------------------------------------------------------------------
__device__ __forceinline__ short f2bs(float x)
{
    __hip_bfloat16 t = __float2bfloat16(x);
    return *(short*)&t;
}
// exact -2x on bf16 bits (exponent bump + sign flip); zero stays zero.
__device__ __forceinline__ short neg2bf(unsigned short v)
{
    return (v & 0x7FFFu) ? (short)((v + 0x0080u) ^ 0x8000u) : (short)0;
}

// ---------------------------------------------------------------------------
__global__ void detect_kernel(const unsigned short* __restrict__ raw,
                              int* __restrict__ flag)
{
    if (threadIdx.x == 0 && blockIdx.x == 0) {
        int cnt = 0;
        for (int i = 0; i < 64; ++i) {
            unsigned int bits = ((unsigned int)raw[2*i]) << 16;
            float v = __uint_as_float(bits);
            float a = fabsf(v);
            if (a > 1e-4f && a < 50.f) ++cnt;
        }
        *flag = (cnt >= 32) ? 1 : 0;
    }
}

__global__ void convert_kernel(const void* __restrict__ src,
                               float* __restrict__ dst, int n,
                               const int* __restrict__ flag)
{
    int i = blockIdx.x * 256 + threadIdx.x;
    if (i >= n) return;
    if (*flag)
        dst[i] = __bfloat162float(((const __hip_bfloat16*)src)[i]);
    else
        dst[i] = ((const float*)src)[i];
}

// ---------------------------------------------------------------------------
__device__ __forceinline__ float distt(const float hi[16], float sqi,
                                       const float* __restrict__ hj)
{
    float4 A = *(const float4*)(hj + 0);
    float4 B = *(const float4*)(hj + 4);
    float4 C = *(const float4*)(hj + 8);
    float4 D = *(const float4*)(hj + 12);
    float sqj = hj[16];
    float d0 = hi[0]*A.x;
    float d1 = hi[1]*A.y;
    d0 = fmaf(hi[2],  A.z, d0);  d1 = fmaf(hi[3],  A.w, d1);
    d0 = fmaf(hi[4],  B.x, d0);  d1 = fmaf(hi[5],  B.y, d1);
    d0 = fmaf(hi[6],  B.z, d0);  d1 = fmaf(hi[7],  B.w, d1);
    d0 = fmaf(hi[8],  C.x, d0);  d1 = fmaf(hi[9],  C.y, d1);
    d0 = fmaf(hi[10], C.z, d0);  d1 = fmaf(hi[11], C.w, d1);
    d0 = fmaf(hi[12], D.x, d0);  d1 = fmaf(hi[13], D.y, d1);
    d0 = fmaf(hi[14], D.z, d0);  d1 = fmaf(hi[15], D.w, d1);
    return fmaf(-2.f, d0 + d1, sqi + sqj);
}

#define LOAD_HI(ptr)                                                        \
    float hi[16]; float sqi;                                                \
    {                                                                       \
        const float* _hr = (ptr);                                           \
        float4 A = *(const float4*)(_hr + 0);                               \
        float4 B = *(const float4*)(_hr + 4);                               \
        float4 C = *(const float4*)(_hr + 8);                               \
        float4 D = *(const float4*)(_hr + 12);                              \
        hi[0]=A.x; hi[1]=A.y; hi[2]=A.z; hi[3]=A.w;                         \
        hi[4]=B.x; hi[5]=B.y; hi[6]=B.z; hi[7]=B.w;                         \
        hi[8]=C.x; hi[9]=C.y; hi[10]=C.z; hi[11]=C.w;                       \
        hi[12]=D.x; hi[13]=D.y; hi[14]=D.z; hi[15]=D.w;                     \
        sqi = _hr[16];                                                      \
    }

// ---------------------------------------------------------------------------
__global__ __launch_bounds__(256) void embed_kernel(
    const float* __restrict__ xf, const float* __restrict__ W,
    const float* __restrict__ b, float* __restrict__ h0)
{
    int i = blockIdx.x * 256 + threadIdx.x;
    float x0 = xf[i*3+0], x1 = xf[i*3+1], x2 = xf[i*3+2];
    float* orow = h0 + i * HPS;
    float sq = 0.f;
#pragma unroll
    for (int c = 0; c < GH; ++c) {
        float t = b[c];
        t = fmaf(x0, W[0*GH+c], t);
        t = fmaf(x1, W[1*GH+c], t);
        t = fmaf(x2, W[2*GH+c], t);
        t = fmaxf(t, 0.f);
        orow[c] = t;
        sq = fmaf(t, t, sq);
    }
    orow[16] = sq;
}

// ---------------------------------------------------------------------------
// h -> bf16 hi/lo split (ha, hb); sq -> bf16 hi/lo split (hs).
__global__ __launch_bounds__(256) void bfsplit_kernel(
    const float* __restrict__ hp, unsigned short* __restrict__ ha,
    unsigned short* __restrict__ hb, unsigned short* __restrict__ hs)
{
    int i = blockIdx.x * 256 + threadIdx.x;     // over GN*16
    int row = i >> 4, f = i & 15;
    float x = hp[row*HPS + f];
    __hip_bfloat16 a = __float2bfloat16(x);
    float af = __bfloat162float(a);
    __hip_bfloat16 b = __float2bfloat16(x - af);
    ha[i] = *(unsigned short*)&a;
    hb[i] = *(unsigned short*)&b;
    if (f == 0) {
        float sq = hp[row*HPS + 16];
        __hip_bfloat16 sa = __float2bfloat16(sq);
        float saf = __bfloat162float(sa);
        __hip_bfloat16 sb = __float2bfloat16(sq - saf);
        hs[row*2 + 0] = *(unsigned short*)&sa;
        hs[row*2 + 1] = *(unsigned short*)&sb;
    }
}

__global__ __launch_bounds__(1024) void sqmax_kernel(
    const float* __restrict__ hp, float* __restrict__ out)
{
    int tid = threadIdx.x;
    float m = 0.f;
    for (int i = tid; i < GN; i += 1024) m = fmaxf(m, hp[i*HPS + 16]);
#pragma unroll
    for (int s = 1; s < 64; s <<= 1) m = fmaxf(m, __shfl_xor(m, s, 64));
    __shared__ float ws[16];
    if ((tid & 63) == 0) ws[tid >> 6] = m;
    __syncthreads();
    if (tid < 16) {
        float v = ws[tid];
#pragma unroll
        for (int s = 1; s < 16; s <<= 1) v = fmaxf(v, __shfl_xor(v, s, 16));
        if (tid == 0) *out = v;
    }
}

// ---------------------------------------------------------------------------
// Probe the 32x32x16 bf16 MFMA empirically (one wave):
//  P1: c=mfma(enc,ones) -> per (lane,reg) row-source lrow (rho)
//  P2: c=mfma(ones,enc) -> col-source lrow (lam)
//  P3: 16 one-hot B-slot probes -> A/B k-slot pairing permutation sp (+inv)
// All validated; any failure -> pbad -> exact rescue path.
__global__ void probe_kernel(int* __restrict__ table, int* __restrict__ spt,
                             int* __restrict__ invt, int* __restrict__ pbad)
{
    const int lane  = threadIdx.x;
    const int lrow  = lane & 31;
    const int lhalf = lane >> 5;
    int badl = 0;

    const short one = f2bs(1.f);
    v8s vone, venc;
#pragma unroll
    for (int e = 0; e < 8; ++e) { vone[e] = one; venc[e] = f2bs((float)(lrow + 1)); }
    const f32x16 z = {0.f,0.f,0.f,0.f,0.f,0.f,0.f,0.f,0.f,0.f,0.f,0.f,0.f,0.f,0.f,0.f};

    f32x16 c1 = __builtin_amdgcn_mfma_f32_32x32x16_bf16(venc, vone, z, 0, 0, 0);
    f32x16 c2 = __builtin_amdgcn_mfma_f32_32x32x16_bf16(vone, venc, z, 0, 0, 0);
#pragma unroll
    for (int reg = 0; reg < 16; ++reg) {
        float fr = c1[reg] * 0.0625f - 1.f;
        float fl = c2[reg] * 0.0625f - 1.f;
        int ri = (int)floorf(fr + 0.5f);
        int li = (int)floorf(fl + 0.5f);
        if (fabsf(fr - (float)ri) > 1e-3f || (unsigned)ri > 31u ||
            fabsf(fl - (float)li) > 1e-3f || (unsigned)li > 31u) badl = 1;
        table[lane*16 + reg] = (ri & 255) | ((li & 255) << 8);
    }

    int mask = 0;
#pragma unroll 1
    for (int m = 0; m < 16; ++m) {
        v8s pa, bh;
#pragma unroll
        for (int e = 0; e < 8; ++e) {
            int s = 8*lhalf + e;
            pa[e] = f2bs((float)(s + 1));
            bh[e] = (s == m) ? one : (short)0;
        }
        f32x16 cp = __builtin_amdgcn_mfma_f32_32x32x16_bf16(pa, bh, z, 0, 0, 0);
        float v0 = cp[0];
        int iv = (int)floorf(v0 + 0.5f);
        int ok = (fabsf(v0 - (float)iv) <= 1e-3f) && iv >= 1 && iv <= 16;
#pragma unroll
        for (int reg = 1; reg < 16; ++reg) ok &= (cp[reg] == v0) ? 1 : 0;
        int iv0 = __shfl(iv, 0, 64);
        ok &= (iv == iv0) ? 1 : 0;
        if (!ok) badl = 1;
        if (lane == 0) spt[m] = iv - 1;
        if (ok) mask |= (1 << (iv - 1));
    }
    unsigned long long bm = __ballot(badl != 0);
    if (lane == 0) {
        int bad = (bm != 0ull || mask != 0xFFFF) ? 1 : 0;
        int inv[16];
        for (int s = 0; s < 16; ++s) inv[s] = s;
        for (int m = 0; m < 16; ++m) {
            int s = spt[m];
            if ((unsigned)s < 16u) inv[s] = m;
        }
        for (int s = 0; s < 16; ++s) invt[s] = inv[s];
        *pbad = bad;
    }
}

// ---------------------------------------------------------------------------
// MFMA kNN: accumulator IS d~ = sqi+sqj-2dot (A pre-scaled -2, sq folded via
// a 4th MFMA) -> no per-column sq decode. Margin-collect superset; exact f32
// recheck + (d,j)-order select. Self-test all 16 regs -> rescue on any doubt.
__global__ __launch_bounds__(256, 2) void knn9_kernel(
    const float* __restrict__ hp,
    const unsigned short* __restrict__ ha, const unsigned short* __restrict__ hb,
    const unsigned short* __restrict__ hs, const float* __restrict__ sqm,
    const int* __restrict__ table, const int* __restrict__ spt,
    const int* __restrict__ invt, const int* __restrict__ pbad,
    int* __restrict__ idxout, int* __restrict__ flags)
{
    __shared__ float    smp[RPB*SSTR];
    __shared__ int      bufj[RPB*BSTR];
    __shared__ unsigned cnt[RPB];
    __shared__ float    t16s[RPB];
    __shared__ int      badsh;

    const int tid   = threadIdx.x;
    const int w     = tid >> 6;
    const int lane  = tid & 63;
    const int lrow  = lane & 31;
    const int lhalf = lane >> 5;
    const int r0    = blockIdx.x * RPB;
    const int gbad  = *pbad;
    const float sqmax = *sqm;
    const short one = f2bs(1.f);
    const f32x16 z = {0.f,0.f,0.f,0.f,0.f,0.f,0.f,0.f,0.f,0.f,0.f,0.f,0.f,0.f,0.f,0.f};

    if (tid == 0) badsh = 0;
    if (tid < RPB) cnt[tid] = 0;
    __syncthreads();

    int pk[16];
    {
        const int4* tp = (const int4*)(table + lane*16);
        int4 a = tp[0], b = tp[1], c = tp[2], d = tp[3];
        pk[0]=a.x; pk[1]=a.y; pk[2]=a.z; pk[3]=a.w;
        pk[4]=b.x; pk[5]=b.y; pk[6]=b.z; pk[7]=b.w;
        pk[8]=c.x; pk[9]=c.y; pk[10]=c.z; pk[11]=c.w;
        pk[12]=d.x; pk[13]=d.y; pk[14]=d.z; pk[15]=d.w;
    }

    // A fragments: gather through inv (k-slot pairing), scale by -2 exactly
    v8s Aa, Ab, As;
    {
        const int base = (r0 + lrow) * 16;
        const int sp0 = spt[0], sp1 = spt[1], sp2 = spt[2], sp3 = spt[3];
        const unsigned si = *(const unsigned*)(hs + (r0 + lrow)*2);
        const short sia = (short)(si & 0xFFFFu), sib = (short)(si >> 16);
#pragma unroll
        for (int e = 0; e < 8; ++e) {
            const int s = 8*lhalf + e;
            const int f = invt[s];
            Aa[e] = neg2bf(ha[base + f]);
            Ab[e] = neg2bf(hb[base + f]);
            short v = 0;
            v = (s == sp0) ? sia : v;
            v = (s == sp1) ? sib : v;
            v = (s == sp2) ? one : v;
            v = (s == sp3) ? one : v;
            As[e] = v;
        }
    }

    // per-reg margin + self-exclusion tile index (phase A)
    float Er[16];
    int tsel[16];
#pragma unroll
    for (int reg = 0; reg < 16; ++reg) {
        const int rho = pk[reg] & 255, lam = (pk[reg] >> 8) & 255;
        Er[reg] = fmaf(EREL, hp[(r0 + rho)*HPS + 16] + sqmax, EABS);
        const int num = r0 + rho - 128*w - 4*lam;
        tsel[reg] = (num >= 0 && (num & 511) == 0) ? (num >> 9) : -1;
    }

    const bool h0 = (lhalf == 0);
    v8s Bz = {0,0,0,0,0,0,0,0};
    if (h0) { Bz[0] = one; Bz[1] = one; }

    // ---- phase A: sampled columns (stride 4); per-(thread,reg) top-2 of d~
    float m1[16], m2[16];
#pragma unroll
    for (int e = 0; e < 16; ++e) { m1[e] = INFF; m2[e] = INFF; }

    for (int t = 0; t < 32; ++t) {
        const int jb = 4*((w + 4*t)*32 + lrow);
        v8s Ba = *(const v8s*)(ha + jb*16 + 8*lhalf);
        v8s Bb = *(const v8s*)(hb + jb*16 + 8*lhalf);
        const unsigned sj = *(const unsigned*)(hs + jb*2);
        v8s Bs = Bz;
        Bs[2] = h0 ? (short)(sj & 0xFFFFu) : (short)0;
        Bs[3] = h0 ? (short)(sj >> 16) : (short)0;
        f32x16 c = __builtin_amdgcn_mfma_f32_32x32x16_bf16(Aa, Ba, z, 0, 0, 0);
        c = __builtin_amdgcn_mfma_f32_32x32x16_bf16(Aa, Bb, c, 0, 0, 0);
        c = __builtin_amdgcn_mfma_f32_32x32x16_bf16(Ab, Ba, c, 0, 0, 0);
        c = __builtin_amdgcn_mfma_f32_32x32x16_bf16(As, Bs, c, 0, 0, 0);
        if (t == 0) {
            // full self-test: all 16 accumulators vs exact f32 distance
#pragma unroll
            for (int reg = 0; reg < 16; ++reg) {
                const int rho = pk[reg] & 255, lam = (pk[reg] >> 8) & 255;
                const int jc = 4*(w*32 + lam);
                if (jc != r0 + rho) {
                    LOAD_HI(hp + (r0 + rho)*HPS);
                    float dex = distt(hi, sqi, hp + jc*HPS);
                    if (!(fabsf(c[reg] - dex) <= Er[reg])) badsh = 1;
                }
            }
        }
#pragma unroll
        for (int reg = 0; reg < 16; ++reg) {
            float v = c[reg];
            if (t == tsel[reg]) v = INFF;
            float hh = fmaxf(m1[reg], v);
            m1[reg] = fminf(m1[reg], v);
            m2[reg] = fminf(m2[reg], hh);
        }
    }
    __syncthreads();
#pragma unroll
    for (int reg = 0; reg < 16; ++reg) {
        const int rho = pk[reg] & 255, lam = (pk[reg] >> 8) & 255;
        smp[rho*SSTR + w*64 + lam*2 + 0] = m1[reg];
        smp[rho*SSTR + w*64 + lam*2 + 1] = m2[reg];
    }
    __syncthreads();

    // ---- merge: 16th smallest of 256 sample d~ per row (8 lanes/row)
    const int mr = tid >> 3, g = tid & 7;
    {
        float sv[32];
#pragma unroll
        for (int e = 0; e < 8; ++e) {
            float4 u = *(const float4*)(smp + mr*SSTR + g*32 + e*4);
            sv[e*4+0] = u.x; sv[e*4+1] = u.y; sv[e*4+2] = u.z; sv[e*4+3] = u.w;
        }
        float tv = INFF;
#pragma unroll
        for (int k = 0; k < 16; ++k) {
            float md = sv[0]; int ms = 0;
#pragma unroll
            for (int e = 1; e < 32; ++e) { bool cs = (sv[e] < md); md = cs ? sv[e] : md; ms = cs ? e : ms; }
            float rv = md; int rl = g;
#pragma unroll
            for (int mm = 1; mm <= 4; mm <<= 1) {
                float ov = __shfl_xor(rv, mm, 8);
                int   ol = __shfl_xor(rl, mm, 8);
                bool cs = (ov < rv) || (ov == rv && ol < rl);
                rv = cs ? ov : rv; rl = cs ? ol : rl;
            }
            tv = rv;
            if (rl == g) {
#pragma unroll
                for (int e = 0; e < 32; ++e) if (e == ms) sv[e] = INFF;
            }
        }
        if (g == 0) t16s[mr] = tv;
    }
    __syncthreads();

    float TR[16];
#pragma unroll
    for (int reg = 0; reg < 16; ++reg)
        TR[reg] = t16s[pk[reg] & 255] + Er[reg];

    // ---- phase B: full scan; collect d~ <= TR (superset of exact top-16;
    // the >=16 phase-A qualifiers re-qualify bit-identically; self collected
    // too -> expect cnt >= 17)
    for (int t = 0; t < 128; ++t) {
        const int jb = (w + 4*t)*32 + lrow;
        v8s Ba = *(const v8s*)(ha + jb*16 + 8*lhalf);
        v8s Bb = *(const v8s*)(hb + jb*16 + 8*lhalf);
        const unsigned sj = *(const unsigned*)(hs + jb*2);
        v8s Bs = Bz;
        Bs[2] = h0 ? (short)(sj & 0xFFFFu) : (short)0;
        Bs[3] = h0 ? (short)(sj >> 16) : (short)0;
        f32x16 c = __builtin_amdgcn_mfma_f32_32x32x16_bf16(Aa, Ba, z, 0, 0, 0);
        c = __builtin_amdgcn_mfma_f32_32x32x16_bf16(Aa, Bb, c, 0, 0, 0);
        c = __builtin_amdgcn_mfma_f32_32x32x16_bf16(Ab, Ba, c, 0, 0, 0);
        c = __builtin_amdgcn_mfma_f32_32x32x16_bf16(As, Bs, c, 0, 0, 0);
        const int jb0 = 32*(w + 4*t);
#pragma unroll
        for (int reg = 0; reg < 16; ++reg) {
            if (c[reg] <= TR[reg]) {
                const int rho = pk[reg] & 255, lam = (pk[reg] >> 8) & 255;
                unsigned pos = atomicAdd(&cnt[rho], 1u);
                if (pos < CAP) bufj[rho*BSTR + pos] = jb0 + lam;
            }
        }
    }
    __syncthreads();

    // ---- exact f32 recheck + top-16 select ((d,j) order, ref-identical)
    {
        const unsigned cc  = cnt[mr];
        const unsigned lim = cc < CAP ? cc : CAP;
        LOAD_HI(hp + (r0 + mr)*HPS);
        float sd[20]; int sj[20];
#pragma unroll
        for (int e = 0; e < 20; ++e) {
            unsigned p = (unsigned)g + 8u*e;
            bool v = p < lim;
            int j = v ? bufj[mr*BSTR + p] : 0x7fffffff;
            if (v && j != r0 + mr) {
                sj[e] = j;
                sd[e] = distt(hi, sqi, hp + j*HPS);
            } else { sd[e] = INFF; sj[e] = 0x7fffffff; }
        }
#pragma unroll
        for (int k = 0; k < GK; ++k) {
            float md = sd[0]; int mj = sj[0]; int ms = 0;
#pragma unroll
            for (int e = 1; e < 20; ++e) {
                bool cs = (sd[e] < md) || (sd[e] == md && sj[e] < mj);
                md = cs ? sd[e] : md; mj = cs ? sj[e] : mj; ms = cs ? e : ms;
            }
            float rd = md; int rj = mj;
#pragma unroll
            for (int mm = 1; mm <= 4; mm <<= 1) {
                float od = __shfl_xor(rd, mm, 8);
                int   oj = __shfl_xor(rj, mm, 8);
                bool cs = (od < rd) || (od == rd && oj < rj);
                rd = cs ? od : rd; rj = cs ? oj : rj;
            }
            if (g == 0) idxout[(r0 + mr)*GK + k] = rj;
            if (rd == md && rj == mj) {
#pragma unroll
                for (int e = 0; e < 20; ++e) if (e == ms) { sd[e] = INFF; sj[e] = 0x7fffffff; }
            }
        }
        if (g == 0)
            flags[r0 + mr] = (cc > CAP || cc < 17u || badsh || gbad) ? 1 : 0;
    }
}

// ---------------------------------------------------------------------------
// Exact full-scan fallback for flagged rows (4 waves; slow-but-correct).
__global__ __launch_bounds__(256) void rescue_kernel(
    const float* __restrict__ hp, const int* __restrict__ flags,
    int* __restrict__ idxout)
{
    const int lane = threadIdx.x & 63;
    const int ww   = threadIdx.x >> 6;
    const int r0 = blockIdx.x * RPB;
    int f = (lane < RPB) ? flags[r0 + lane] : 0;
    if (__ballot(f != 0) == 0ull) return;
    for (int rr = ww; rr < RPB; rr += 4) {
        if (flags[r0 + rr] == 0) continue;
        const int row = r0 + rr;
        LOAD_HI(hp + row * HPS);
        float topd[GK]; int topi[GK];
#pragma unroll
        for (int s = 0; s < GK; ++s) { topd[s] = INFF; topi[s] = -1; }
        float mx = INFF; int mxs = 0;
        for (int s = 0; s < GN/64; ++s) {
            int j = lane + (s << 6);
            float d = distt(hi, sqi, hp + j * HPS);
            if (j == row) d = INFF;
            if (d < mx) {
#pragma unroll
                for (int e = 0; e < GK; ++e) { bool cs = (e == mxs); topd[e] = cs ? d : topd[e]; topi[e] = cs ? j : topi[e]; }
                mx = topd[0]; mxs = 0;
#pragma unroll
                for (int e = 1; e < GK; ++e) { bool cs = (topd[e] >= mx); mx = cs ? topd[e] : mx; mxs = cs ? e : mxs; }
            }
        }
#pragma unroll
        for (int t = 0; t < GK; ++t) {
            float md = topd[0]; int mj = topi[0]; int ms = 0;
#pragma unroll
            for (int e = 1; e < GK; ++e) {
                bool cs = (topd[e] < md) || (topd[e] == md && topi[e] < mj);
                md = cs ? topd[e] : md; mj = cs ? topi[e] : mj; ms = cs ? e : ms;
            }
            float rd = md; int rj = mj;
#pragma unroll
            for (int m = 1; m <= 32; m <<= 1) {
                float od = __shfl_xor(rd, m, 64);
                int   oj = __shfl_xor(rj, m, 64);
                bool cs = (od < rd) || (od == rd && oj < rj);
                rd = cs ? od : rd; rj = cs ? oj : rj;
            }
            if (lane == 0) idxout[row*GK + t] = rj;
            if (rd == md && rj == mj) {
#pragma unroll
                for (int e = 0; e < GK; ++e) if (e == ms) { topd[e] = INFF; topi[e] = 0x7fffffff; }
            }
        }
    }
}

// ---------------------------------------------------------------------------
__global__ __launch_bounds__(256) void edgeconv_kernel(
    const float* __restrict__ hin, const int* __restrict__ idx,
    const float* __restrict__ W1, const float* __restrict__ b1,
    const float* __restrict__ W2, const float* __restrict__ b2,
    float* __restrict__ hout)
{
    __shared__ float sW1[2*GH*GH], sW2[GH*GH], sb1[GH], sb2[GH];
    const int tid = threadIdx.x;
    for (int t = tid; t < 2*GH*GH; t += 256) sW1[t] = W1[t];
    for (int t = tid; t < GH*GH;  t += 256) sW2[t] = W2[t];
    if (tid < GH) { sb1[tid] = b1[tid]; sb2[tid] = b2[tid]; }
    __syncthreads();

    const int t4 = tid & 3;
    const int i = blockIdx.x * 64 + (tid >> 2);

    LOAD_HI(hin + i * HPS);
    (void)sqi;
    float ci[GH];
#pragma unroll
    for (int c = 0; c < GH; ++c) {
        float s = sb1[c];
#pragma unroll
        for (int d = 0; d < GH; ++d) s = fmaf(hi[d], sW1[d*GH+c], s);
        ci[c] = s;
    }
    float acc[GH];
#pragma unroll
    for (int c = 0; c < GH; ++c) acc[c] = 0.f;

    const int4 jj = *(const int4*)(idx + i*GK + t4*4);
    const int js[4] = { jj.x, jj.y, jj.z, jj.w };
#pragma unroll
    for (int nn = 0; nn < 4; ++nn) {
        const int j = js[nn];
        float dj[GH];
        {
            const float* hv = hin + j * HPS;
            float4 A = *(const float4*)(hv + 0);
            float4 B = *(const float4*)(hv + 4);
            float4 C = *(const float4*)(hv + 8);
            float4 D = *(const float4*)(hv + 12);
            dj[0]=A.x-hi[0]; dj[1]=A.y-hi[1]; dj[2]=A.z-hi[2]; dj[3]=A.w-hi[3];
            dj[4]=B.x-hi[4]; dj[5]=B.y-hi[5]; dj[6]=B.z-hi[6]; dj[7]=B.w-hi[7];
            dj[8]=C.x-hi[8]; dj[9]=C.y-hi[9]; dj[10]=C.z-hi[10]; dj[11]=C.w-hi[11];
            dj[12]=D.x-hi[12]; dj[13]=D.y-hi[13]; dj[14]=D.z-hi[14]; dj[15]=D.w-hi[15];
        }
        float msg[GH];
#pragma unroll
        for (int c = 0; c < GH; ++c) {
            float s = ci[c];
#pragma unroll
            for (int d = 0; d < GH; ++d) s = fmaf(dj[d], sW1[(GH+d)*GH+c], s);
            msg[c] = fmaxf(s, 0.f);
        }
#pragma unroll
        for (int c2 = 0; c2 < GH; ++c2) {
            float s = acc[c2];
#pragma unroll
            for (int c = 0; c < GH; ++c) s = fmaf(msg[c], sW2[c*GH+c2], s);
            acc[c2] = s;
        }
    }
#pragma unroll
    for (int c = 0; c < GH; ++c) {
        acc[c] += __shfl_xor(acc[c], 1);
        acc[c] += __shfl_xor(acc[c], 2);
    }
    if (t4 == 0) {
        float* orow = hout + i * HPS;
        float sq = 0.f;
#pragma unroll
        for (int c = 0; c < GH; ++c) {
            float v = acc[c] * (1.f/16.f) + sb2[c];
            orow[c] = v;
            sq = fmaf(v, v, sq);
        }
        orow[16] = sq;
    }
}

// ---------------------------------------------------------------------------
__global__ __launch_bounds__(256) void out_kernel(
    const float* __restrict__ hbase, const float* __restrict__ W,
    const float* __restrict__ b, void* __restrict__ out,
    const int* __restrict__ flag)
{
    int i = blockIdx.x * 256 + threadIdx.x;
    float a0 = b[0], a1 = b[1], a2 = b[2];
#pragma unroll
    for (int l = 0; l < GL; ++l) {
        const float* hp = hbase + l * GN * HPS + i * HPS;
#pragma unroll
        for (int c = 0; c < GH; ++c) {
            const float v = hp[c];
            const float* wr = W + (l * GH + c) * 3;
            a0 = fmaf(v, wr[0], a0);
            a1 = fmaf(v, wr[1], a1);
            a2 = fmaf(v, wr[2], a2);
        }
    }
    if (*flag) {
        __hip_bfloat16* o = (__hip_bfloat16*)out;
        o[i*3+0] = __float2bfloat16(a0);
        o[i*3+1] = __float2bfloat16(a1);
        o[i*3+2] = __float2bfloat16(a2);
    } else {
        float* o = (float*)out;
        o[i*3+0] = a0; o[i*3+1] = a1; o[i*3+2] = a2;
    }
}

// ---------------------------------------------------------------------------
extern "C" void kernel_launch(void* const* d_in, const int* in_sizes, int n_in,
                              void* d_out, int out_size, void* d_ws, size_t ws_size,
                              hipStream_t stream)
{
    float* wsf  = (float*)d_ws;
    int* idxb   = (int*)(wsf + OFF_IDX);
    int* flagsb = (int*)(wsf + OFF_FLAGS);
    int* dflag  = (int*)(wsf + OFF_DFLAG);
    unsigned short* ha = (unsigned short*)(wsf + OFF_HA);
    unsigned short* hb = (unsigned short*)(wsf + OFF_HB);
    unsigned short* hs = (unsigned short*)(wsf + OFF_HS);
    int* tab    = (int*)(wsf + OFF_TAB);
    int* pbad   = (int*)(wsf + OFF_PBAD);
    int* spt    = (int*)(wsf + OFF_SP);
    int* invt   = (int*)(wsf + OFF_INV);
    float* sqmp = wsf + OFF_SQM;

    detect_kernel<<<1, 64, 0, stream>>>((const unsigned short*)d_in[0], dflag);
    probe_kernel<<<1, 64, 0, stream>>>(tab, spt, invt, pbad);

    const int segoff[9] = {OFF_XF, OFF_EMBW, OFF_EMBB, OFF_W1, OFF_B1,
                           OFF_W2, OFF_B2, OFF_OW, OFF_OB};
    const int segn[9]   = {GN*3, 3*GH, GH, GL*2*GH*GH, GL*GH,
                           GL*GH*GH, GL*GH, GL*GH*3, 3};
    for (int s = 0; s < 9; ++s)
        convert_kernel<<<(segn[s] + 255)/256, 256, 0, stream>>>(
            d_in[s], wsf + segoff[s], segn[s], dflag);

    embed_kernel<<<GN/256, 256, 0, stream>>>(
        wsf + OFF_XF, wsf + OFF_EMBW, wsf + OFF_EMBB, wsf + OFF_H);

    for (int l = 0; l < GL; ++l) {
        const float* hin = wsf + OFF_H + l*GN*HPS;
        float* hout      = wsf + OFF_H + (l+1)*GN*HPS;
        bfsplit_kernel<<<GN*GH/256, 256, 0, stream>>>(hin, ha, hb, hs);
        sqmax_kernel<<<1, 1024, 0, stream>>>(hin, sqmp);
        knn9_kernel<<<GN/RPB, 256, 0, stream>>>(hin, ha, hb, hs, sqmp,
                                                tab, spt, invt, pbad,
                                                idxb, flagsb);
        rescue_kernel<<<GN/RPB, 256, 0, stream>>>(hin, flagsb, idxb);
        edgeconv_kernel<<<GN/64, 256, 0, stream>>>(hin, idxb,
            wsf + OFF_W1 + l*2*GH*GH, wsf + OFF_B1 + l*GH,
            wsf + OFF_W2 + l*GH*GH,  wsf + OFF_B2 + l*GH, hout);
    }

    out_kernel<<<GN/256, 256, 0, stream>>>(
        wsf + OFF_H + GN*HPS, wsf + OFF_OW, wsf + OFF_OB, d_out, dflag);
}